// Round 1
// baseline (24598.051 us; speedup 1.0000x reference)
//
#include <hip/hip_runtime.h>
#include <stdint.h>

// ---------------- geometry ----------------
// B=1024, T=512, I=64, H=256, gates 4H=1024 (i,f,g,o)
// 256 blocks = 16 slices (s) x 16 batch-groups (g); bid = s*16 + g
//   -> all 16 blocks of a group land on one XCD (bid%8 dispatch)
// block: 256 threads = 4 waves; wave w owns batch rows [g*64+w*16, +16)
// slice s owns h-columns [s*16, s*16+16) of BOTH layers (gate rows
//   {n*256 + s*16 + c : n in 0..3, c in 0..15})
// LDS: weight slice in MFMA B-fragment order, bf16:
//   L0: K = 64(x) + 256(h0) = 320 -> 10 chunks of 32
//   L1: K = 256(h0) + 256(h1)=512 -> 16 chunks
//   frag(layer,n,chunk) = 64 lanes x 8 bf16 (1KB) ; total 104KB

#define T_STEPS 512
#define NC0 10
#define NC1 16
#define WSLICE_ELEMS (4*(NC0+NC1)*512)   // 53248 bf16 elems = 104KB
#define L1_OFF (4*NC0*512)               // 20480
#define HN (1024*256)                    // elems per h array

typedef __attribute__((ext_vector_type(8))) short short8;
typedef __attribute__((ext_vector_type(4))) float floatx4;

__device__ __forceinline__ uint32_t f2bf(float f){
  uint32_t u = __builtin_bit_cast(uint32_t, f);
  return (u + 0x7fffu + ((u >> 16) & 1u)) >> 16;   // RNE, finite data only
}
__device__ __forceinline__ float bf2f(uint32_t b){
  return __builtin_bit_cast(float, b << 16);
}
__device__ __forceinline__ float sigm(float x){
  return __builtin_amdgcn_rcpf(1.0f + __builtin_amdgcn_exp2f(-1.44269504f*x));
}
__device__ __forceinline__ float tanhf_(float x){
  // tanh = 1 - 2/(e^{2x}+1); saturates correctly at +-inf of exp2
  return 1.0f - 2.0f*__builtin_amdgcn_rcpf(1.0f + __builtin_amdgcn_exp2f(2.88539008f*x));
}
__device__ __forceinline__ floatx4 splat4(float v){ return (floatx4){v,v,v,v}; }

// 16-block group barrier: monotone counter, device-scope
__device__ __forceinline__ void group_barrier(int* c, int target){
  __syncthreads();                       // drains all waves' vmem (waitcnt before s_barrier)
  if (threadIdx.x == 0){
    __threadfence();                     // release: publish h slices
    __hip_atomic_fetch_add(c, 1, __ATOMIC_RELEASE, __HIP_MEMORY_SCOPE_AGENT);
    int spins = 0;
    while (__hip_atomic_load(c, __ATOMIC_ACQUIRE, __HIP_MEMORY_SCOPE_AGENT) < target){
      if (++spins > (1<<22)) break;      // bounded: fail loud, never hang
      __builtin_amdgcn_s_sleep(1);
    }
    __threadfence();                     // acquire: invalidate L1 before peer reads
  }
  __syncthreads();
}

// ---------------- prep: gather weights into per-slice B-fragment images ----------------
extern "C" __global__ void prep_weights(const float* __restrict__ wih0, const float* __restrict__ whh0,
                                        const float* __restrict__ wih1, const float* __restrict__ whh1,
                                        uint16_t* __restrict__ wfrag)
{
  int idx = blockIdx.x*256 + threadIdx.x;     // exactly 16*WSLICE_ELEMS threads
  int s  = idx / WSLICE_ELEMS;
  int r  = idx - s*WSLICE_ELEMS;
  int layer = (r >= L1_OFF) ? 1 : 0;
  int rr = layer ? (r - L1_OFF) : r;
  int nc = layer ? NC1 : NC0;
  int n  = rr / (nc*512);
  int c  = (rr / 512) % nc;
  int l  = (rr >> 3) & 63;
  int j  = rr & 7;
  int k  = c*32 + ((l >> 4) << 3) + j;        // B frag: lane l holds col=l&15, k=8*(l>>4)+j
  int grow = n*256 + s*16 + (l & 15);
  float v;
  if (!layer) v = (k < 64)  ? wih0[grow*64  + k] : whh0[grow*256 + (k - 64)];
  else        v = (k < 256) ? wih1[grow*256 + k] : whh1[grow*256 + (k - 256)];
  wfrag[idx] = (uint16_t)f2bf(v);
}

extern "C" __global__ void prep_bias(const float* __restrict__ bih0, const float* __restrict__ bhh0,
                                     const float* __restrict__ bih1, const float* __restrict__ bhh1,
                                     float* __restrict__ biasg)
{
  int idx = blockIdx.x*256 + threadIdx.x;     // 16 slices * 2 layers * 64
  if (idx >= 16*2*64) return;
  int s = idx >> 7;
  int layer = (idx >> 6) & 1;
  int q = idx & 63;
  int grow = (q >> 4)*256 + s*16 + (q & 15);
  biasg[idx] = layer ? (bih1[grow] + bhh1[grow]) : (bih0[grow] + bhh0[grow]);
}

// ---------------- main persistent cooperative kernel ----------------
extern "C" __global__ void __launch_bounds__(256, 1)
lstm_main(const float* __restrict__ x,
          const uint16_t* __restrict__ wfrag,
          const float* __restrict__ biasg,
          uint16_t* __restrict__ hbase,
          const float* __restrict__ fcw,
          const float* __restrict__ fcb,
          int* __restrict__ ctr,
          float* __restrict__ out)
{
  extern __shared__ uint16_t wlds[];
  const int tid  = threadIdx.x;
  const int bid  = blockIdx.x;
  const int s    = bid >> 4;
  const int g    = bid & 15;
  const int wv   = tid >> 6;
  const int lane = tid & 63;

  { // stage weight slice (104KB) into LDS, 16B per thread per iter
    const uint16_t* wsrc = wfrag + (size_t)s*WSLICE_ELEMS;
    for (int i = tid*8; i < WSLICE_ELEMS; i += 256*8)
      *(short8*)(wlds + i) = *(const short8*)(wsrc + i);
  }
  float b0[4], b1[4];
  {
    const int col = lane & 15;
    #pragma unroll
    for (int n = 0; n < 4; ++n){
      b0[n] = biasg[(s*2+0)*64 + n*16 + col];
      b1[n] = biasg[(s*2+1)*64 + n*16 + col];
    }
  }
  __syncthreads();

  // A-frag addressing: lane holds row = lane&15 (+wave base), k = 8*(lane>>4)+j
  const int arow = g*64 + wv*16 + (lane & 15);
  const int ka   = (lane >> 4) * 8;
  // D-frag addressing (verified m89): col = lane&15, row = 4*(lane>>4)+reg
  const int drow = g*64 + wv*16 + ((lane >> 4) << 2);
  const int dcol = s*16 + (lane & 15);

  uint16_t* h0hi[2] = { hbase + 0*(size_t)HN, hbase + 1*(size_t)HN };
  uint16_t* h0lo[2] = { hbase + 2*(size_t)HN, hbase + 3*(size_t)HN };
  uint16_t* h1hi[2] = { hbase + 4*(size_t)HN, hbase + 5*(size_t)HN };
  uint16_t* h1lo[2] = { hbase + 6*(size_t)HN, hbase + 7*(size_t)HN };

  float c0[4] = {0,0,0,0}, c1[4] = {0,0,0,0};
  int* myc = ctr + g;

  short8 ahi[NC1], alo[NC1];

  for (int t = 0; t < T_STEPS; ++t){
    const int par = t & 1, rpar = par ^ 1;

    // ================= layer 0: gates = bias + x(t)W_ih0^T + h0(t-1)W_hh0^T =================
    floatx4 acc[4];
    #pragma unroll
    for (int n = 0; n < 4; ++n) acc[n] = splat4(b0[n]);
    {
      const float* xp = x + ((size_t)arow*T_STEPS + t)*64 + ka;
      #pragma unroll
      for (int kc = 0; kc < 2; ++kc){            // x: k 0..63 -> chunks 0,1 (split hi/lo)
        floatx4 v0 = *(const floatx4*)(xp + kc*32);
        floatx4 v1 = *(const floatx4*)(xp + kc*32 + 4);
        #pragma unroll
        for (int j = 0; j < 8; ++j){
          float f = (j < 4) ? v0[j] : v1[j-4];
          uint32_t hb = f2bf(f);
          float fh = bf2f(hb);
          uint32_t lb = f2bf(f - fh);
          ahi[kc][j] = (short)hb; alo[kc][j] = (short)lb;
        }
      }
      const uint16_t* ph = h0hi[rpar] + (size_t)arow*256 + ka;
      const uint16_t* pl = h0lo[rpar] + (size_t)arow*256 + ka;
      #pragma unroll
      for (int kc = 0; kc < 8; ++kc){            // h0 old: chunks 2..9
        ahi[2+kc] = *(const short8*)(ph + kc*32);
        alo[2+kc] = *(const short8*)(pl + kc*32);
      }
    }
    #pragma unroll
    for (int pk = 0; pk < NC0; ++pk){
      #pragma unroll
      for (int n = 0; n < 4; ++n){
        short8 bfr = *(const short8*)(wlds + (n*NC0 + pk)*512 + lane*8);
        acc[n] = __builtin_amdgcn_mfma_f32_16x16x32_bf16(ahi[pk], bfr, acc[n], 0, 0, 0);
        acc[n] = __builtin_amdgcn_mfma_f32_16x16x32_bf16(alo[pk], bfr, acc[n], 0, 0, 0);
      }
    }
    { // LSTM pointwise + publish h0 slice (hi/lo bf16)
      uint16_t* qh = h0hi[par]; uint16_t* ql = h0lo[par];
      #pragma unroll
      for (int r = 0; r < 4; ++r){
        float ig = sigm(acc[0][r]);
        float fg = sigm(acc[1][r]);
        float gg = tanhf_(acc[2][r]);
        float og = sigm(acc[3][r]);
        c0[r] = fg*c0[r] + ig*gg;
        float h = og*tanhf_(c0[r]);
        uint32_t hb = f2bf(h); float fh = bf2f(hb); uint32_t lb = f2bf(h - fh);
        size_t idx = (size_t)(drow + r)*256 + dcol;
        qh[idx] = (uint16_t)hb; ql[idx] = (uint16_t)lb;
      }
    }
    group_barrier(myc, 16*(2*t+1));

    // ================= layer 1: gates = bias + h0(t)W_ih1^T + h1(t-1)W_hh1^T =================
    #pragma unroll
    for (int n = 0; n < 4; ++n) acc[n] = splat4(b1[n]);
    {
      const uint16_t* p0h = h0hi[par]  + (size_t)arow*256 + ka;
      const uint16_t* p0l = h0lo[par]  + (size_t)arow*256 + ka;
      const uint16_t* p1h = h1hi[rpar] + (size_t)arow*256 + ka;
      const uint16_t* p1l = h1lo[rpar] + (size_t)arow*256 + ka;
      #pragma unroll
      for (int kc = 0; kc < 8; ++kc){
        ahi[kc]   = *(const short8*)(p0h + kc*32);
        alo[kc]   = *(const short8*)(p0l + kc*32);
        ahi[8+kc] = *(const short8*)(p1h + kc*32);
        alo[8+kc] = *(const short8*)(p1l + kc*32);
      }
    }
    #pragma unroll
    for (int pk = 0; pk < NC1; ++pk){
      #pragma unroll
      for (int n = 0; n < 4; ++n){
        short8 bfr = *(const short8*)(wlds + L1_OFF + (n*NC1 + pk)*512 + lane*8);
        acc[n] = __builtin_amdgcn_mfma_f32_16x16x32_bf16(ahi[pk], bfr, acc[n], 0, 0, 0);
        acc[n] = __builtin_amdgcn_mfma_f32_16x16x32_bf16(alo[pk], bfr, acc[n], 0, 0, 0);
      }
    }
    {
      uint16_t* qh = h1hi[par]; uint16_t* ql = h1lo[par];
      #pragma unroll
      for (int r = 0; r < 4; ++r){
        float ig = sigm(acc[0][r]);
        float fg = sigm(acc[1][r]);
        float gg = tanhf_(acc[2][r]);
        float og = sigm(acc[3][r]);
        c1[r] = fg*c1[r] + ig*gg;
        float h = og*tanhf_(c1[r]);
        uint32_t hb = f2bf(h); float fh = bf2f(hb); uint32_t lb = f2bf(h - fh);
        size_t idx = (size_t)(drow + r)*256 + dcol;
        qh[idx] = (uint16_t)hb; ql[idx] = (uint16_t)lb;
      }
    }
    group_barrier(myc, 16*(2*t+2));
  }

  // ---------------- FC epilogue: out[b] = h1_final(b,:) . fcw + fcb ----------------
  if (s == 0){
    const uint16_t* fh = h1hi[1];   // t=511 -> parity 1
    const uint16_t* fl = h1lo[1];
    const int rl = tid >> 2, seg = tid & 3;
    const int row = g*64 + rl;
    float sum = 0.f;
    for (int k = seg*64; k < seg*64 + 64; ++k){
      float hv = bf2f(fh[(size_t)row*256 + k]) + bf2f(fl[(size_t)row*256 + k]);
      sum += hv * fcw[k];
    }
    sum += __shfl_down(sum, 1);
    sum += __shfl_down(sum, 2);
    if (seg == 0) out[row] = sum + fcb[0];
  }
}

// ---------------- host launch ----------------
extern "C" void kernel_launch(void* const* d_in, const int* in_sizes, int n_in,
                              void* d_out, int out_size, void* d_ws, size_t ws_size,
                              hipStream_t stream)
{
  (void)in_sizes; (void)n_in; (void)out_size; (void)ws_size;
  const float* x    = (const float*)d_in[0];
  const float* wih0 = (const float*)d_in[1];
  const float* whh0 = (const float*)d_in[2];
  const float* bih0 = (const float*)d_in[3];
  const float* bhh0 = (const float*)d_in[4];
  const float* wih1 = (const float*)d_in[5];
  const float* whh1 = (const float*)d_in[6];
  const float* bih1 = (const float*)d_in[7];
  const float* bhh1 = (const float*)d_in[8];
  const float* fcw  = (const float*)d_in[9];
  const float* fcb  = (const float*)d_in[10];

  char* ws = (char*)d_ws;
  const size_t SZ_WFRAG = (size_t)16*WSLICE_ELEMS*2;     // 1,703,936
  const size_t OFF_BIAS = SZ_WFRAG;                      // 8KB of biases
  const size_t OFF_CTR  = OFF_BIAS + (size_t)16*2*64*4;  // 1,712,128
  const size_t OFF_H    = (size_t)2*1024*1024;           // h buffers: 8 x 512KB

  uint16_t* wfrag = (uint16_t*)(ws);
  float*    biasg = (float*)(ws + OFF_BIAS);
  int*      ctr   = (int*)(ws + OFF_CTR);
  uint16_t* hbase = (uint16_t*)(ws + OFF_H);
  float*    out   = (float*)d_out;

  // zero barrier counters + all h double-buffers (t=0 reads zeros; counters must restart)
  hipMemsetAsync(ws + OFF_CTR, 0, (OFF_H - OFF_CTR) + (size_t)8*HN*2, stream);

  hipLaunchKernelGGL(prep_weights, dim3(16*WSLICE_ELEMS/256), dim3(256), 0, stream,
                     wih0, whh0, wih1, whh1, wfrag);
  hipLaunchKernelGGL(prep_bias, dim3(8), dim3(256), 0, stream,
                     bih0, bhh0, bih1, bhh1, biasg);

  hipFuncSetAttribute((const void*)lstm_main,
                      hipFuncAttributeMaxDynamicSharedMemorySize, WSLICE_ELEMS*2);
  void* args[] = { (void*)&x, (void*)&wfrag, (void*)&biasg, (void*)&hbase,
                   (void*)&fcw, (void*)&fcb, (void*)&ctr, (void*)&out };
  hipLaunchCooperativeKernel((void*)lstm_main, dim3(256), dim3(256),
                             args, WSLICE_ELEMS*2, stream);
}

// Round 2
// 5389.907 us; speedup vs baseline: 4.5637x; 4.5637x over previous
//
#include <hip/hip_runtime.h>
#include <stdint.h>

// ---------------- geometry ----------------
// B=1024, T=512, I=64, H=256, gates 4H=1024 (i,f,g,o)
// 256 blocks = 16 slices (s) x 16 batch-groups (g); bid = s*16 + g
// block: 256 threads = 4 waves; wave w owns batch rows [g*64+w*16, +16)
// slice s owns h-columns [s*16, s*16+16) of BOTH layers
// LDS: weight slice in MFMA B-fragment order, bf16 (104KB), resident all run.
// h exchange between the 16 blocks of a group: device-coherent (sc0 sc1)
// loads/stores -> coherence point is memory-side L3; NO cache fences.

#define T_STEPS 512
#define NC0 10
#define NC1 16
#define WSLICE_ELEMS (4*(NC0+NC1)*512)   // 53248 bf16 elems = 104KB
#define L1_OFF (4*NC0*512)               // 20480
#define HN (1024*256)                    // elems per h array

typedef __attribute__((ext_vector_type(8))) short short8;
typedef __attribute__((ext_vector_type(4))) float floatx4;

__device__ __forceinline__ uint32_t f2bf(float f){
  uint32_t u = __builtin_bit_cast(uint32_t, f);
  return (u + 0x7fffu + ((u >> 16) & 1u)) >> 16;   // RNE, finite data only
}
__device__ __forceinline__ float bf2f(uint32_t b){
  return __builtin_bit_cast(float, b << 16);
}
__device__ __forceinline__ float sigm(float x){
  return __builtin_amdgcn_rcpf(1.0f + __builtin_amdgcn_exp2f(-1.44269504f*x));
}
__device__ __forceinline__ float tanhf_(float x){
  return 1.0f - 2.0f*__builtin_amdgcn_rcpf(1.0f + __builtin_amdgcn_exp2f(2.88539008f*x));
}
__device__ __forceinline__ floatx4 splat4(float v){ return (floatx4){v,v,v,v}; }

// ---- device-coherent accesses (bypass L1+L2; coherent at memory-side L3) ----
__device__ __forceinline__ short8 load_coh16(const uint16_t* p){
  short8 r;
  asm volatile("global_load_dwordx4 %0, %1, off sc0 sc1" : "=v"(r) : "v"(p));
  return r;
}
__device__ __forceinline__ void store_coh2(uint16_t* p, uint32_t v){
  asm volatile("global_store_short %0, %1, off sc0 sc1" :: "v"(p), "v"(v) : "memory");
}
__device__ __forceinline__ void vm_drain(){
  asm volatile("s_waitcnt vmcnt(0)" ::: "memory");
  __builtin_amdgcn_sched_barrier(0);   // keep consumers below the wait (rule #18)
}

// 16-block group barrier: relaxed agent atomics only; h data coherence is
// provided by the sc0/sc1 data path + vmcnt write-ack, NOT by fences.
__device__ __forceinline__ void group_barrier(int* c, int target){
  vm_drain();                          // each thread's coherent stores are globally visible
  __syncthreads();
  if (threadIdx.x == 0){
    __hip_atomic_fetch_add(c, 1, __ATOMIC_RELAXED, __HIP_MEMORY_SCOPE_AGENT);
    int spins = 0;
    while (__hip_atomic_load(c, __ATOMIC_RELAXED, __HIP_MEMORY_SCOPE_AGENT) < target){
      if (++spins > (1<<24)) break;    // bounded: fail loud, never hang
      __builtin_amdgcn_s_sleep(1);
    }
  }
  __syncthreads();
}

// ---------------- prep: gather weights into per-slice B-fragment images ----------------
extern "C" __global__ void prep_weights(const float* __restrict__ wih0, const float* __restrict__ whh0,
                                        const float* __restrict__ wih1, const float* __restrict__ whh1,
                                        uint16_t* __restrict__ wfrag)
{
  int idx = blockIdx.x*256 + threadIdx.x;     // exactly 16*WSLICE_ELEMS threads
  int s  = idx / WSLICE_ELEMS;
  int r  = idx - s*WSLICE_ELEMS;
  int layer = (r >= L1_OFF) ? 1 : 0;
  int rr = layer ? (r - L1_OFF) : r;
  int nc = layer ? NC1 : NC0;
  int n  = rr / (nc*512);
  int c  = (rr / 512) % nc;
  int l  = (rr >> 3) & 63;
  int j  = rr & 7;
  int k  = c*32 + ((l >> 4) << 3) + j;        // B frag: lane l holds col=l&15, k=8*(l>>4)+j
  int grow = n*256 + s*16 + (l & 15);
  float v;
  if (!layer) v = (k < 64)  ? wih0[grow*64  + k] : whh0[grow*256 + (k - 64)];
  else        v = (k < 256) ? wih1[grow*256 + k] : whh1[grow*256 + (k - 256)];
  wfrag[idx] = (uint16_t)f2bf(v);
}

extern "C" __global__ void prep_bias(const float* __restrict__ bih0, const float* __restrict__ bhh0,
                                     const float* __restrict__ bih1, const float* __restrict__ bhh1,
                                     float* __restrict__ biasg)
{
  int idx = blockIdx.x*256 + threadIdx.x;     // 16 slices * 2 layers * 64
  if (idx >= 16*2*64) return;
  int s = idx >> 7;
  int layer = (idx >> 6) & 1;
  int q = idx & 63;
  int grow = (q >> 4)*256 + s*16 + (q & 15);
  biasg[idx] = layer ? (bih1[grow] + bhh1[grow]) : (bih0[grow] + bhh0[grow]);
}

// ---------------- main persistent cooperative kernel ----------------
extern "C" __global__ void __launch_bounds__(256, 1)
lstm_main(const float* __restrict__ x,
          const uint16_t* __restrict__ wfrag,
          const float* __restrict__ biasg,
          uint16_t* __restrict__ hbase,
          const float* __restrict__ fcw,
          const float* __restrict__ fcb,
          int* __restrict__ ctr,
          float* __restrict__ out)
{
  extern __shared__ uint16_t wlds[];
  const int tid  = threadIdx.x;
  const int bid  = blockIdx.x;
  const int s    = bid >> 4;
  const int g    = bid & 15;
  const int wv   = tid >> 6;
  const int lane = tid & 63;

  { // stage weight slice (104KB) into LDS
    const uint16_t* wsrc = wfrag + (size_t)s*WSLICE_ELEMS;
    for (int i = tid*8; i < WSLICE_ELEMS; i += 256*8)
      *(short8*)(wlds + i) = *(const short8*)(wsrc + i);
  }
  float b0[4], b1[4];
  {
    const int col = lane & 15;
    #pragma unroll
    for (int n = 0; n < 4; ++n){
      b0[n] = biasg[(s*2+0)*64 + n*16 + col];
      b1[n] = biasg[(s*2+1)*64 + n*16 + col];
    }
  }
  __syncthreads();

  // A-frag addressing: lane holds row = lane&15 (+wave base), k = 8*(lane>>4)+j
  const int arow = g*64 + wv*16 + (lane & 15);
  const int ka   = (lane >> 4) * 8;
  // D-frag addressing: col = lane&15, row = 4*(lane>>4)+reg
  const int drow = g*64 + wv*16 + ((lane >> 4) << 2);
  const int dcol = s*16 + (lane & 15);

  uint16_t* h0hi[2] = { hbase + 0*(size_t)HN, hbase + 1*(size_t)HN };
  uint16_t* h0lo[2] = { hbase + 2*(size_t)HN, hbase + 3*(size_t)HN };
  uint16_t* h1hi[2] = { hbase + 4*(size_t)HN, hbase + 5*(size_t)HN };
  uint16_t* h1lo[2] = { hbase + 6*(size_t)HN, hbase + 7*(size_t)HN };

  float c0[4] = {0,0,0,0}, c1[4] = {0,0,0,0};
  int* myc = ctr + g*32;               // 128B apart: no line sharing between groups

  short8 ahi[NC0], alo[NC0];           // layer-0: x(2) + h0old(8); layer-1 reuses [0..7]
  short8 bh[8],  bl[8];                // h1old, prefetched at iteration start

  for (int t = 0; t < T_STEPS; ++t){
    const int par = t & 1, rpar = par ^ 1;

    // ---- x(t) -> hi/lo bf16 chunks 0..1 (normal cached loads) ----
    {
      const float* xp = x + ((size_t)arow*T_STEPS + t)*64 + ka;
      #pragma unroll
      for (int kc = 0; kc < 2; ++kc){
        floatx4 v0 = *(const floatx4*)(xp + kc*32);
        floatx4 v1 = *(const floatx4*)(xp + kc*32 + 4);
        #pragma unroll
        for (int j = 0; j < 8; ++j){
          float f = (j < 4) ? v0[j] : v1[j-4];
          uint32_t hb = f2bf(f);
          float fh = bf2f(hb);
          uint32_t lb = f2bf(f - fh);
          ahi[kc][j] = (short)hb; alo[kc][j] = (short)lb;
        }
      }
    }
    // ---- issue coherent loads: h0(t-1) [layer-0] and h1(t-1) [layer-1 prefetch] ----
    {
      const uint16_t* ph  = h0hi[rpar] + (size_t)arow*256 + ka;
      const uint16_t* pl  = h0lo[rpar] + (size_t)arow*256 + ka;
      const uint16_t* p1h = h1hi[rpar] + (size_t)arow*256 + ka;
      const uint16_t* p1l = h1lo[rpar] + (size_t)arow*256 + ka;
      #pragma unroll
      for (int kc = 0; kc < 8; ++kc){
        ahi[2+kc] = load_coh16(ph  + kc*32);
        alo[2+kc] = load_coh16(pl  + kc*32);
        bh[kc]    = load_coh16(p1h + kc*32);
        bl[kc]    = load_coh16(p1l + kc*32);
      }
    }

    // ================= layer 0 =================
    floatx4 acc[4];
    #pragma unroll
    for (int n = 0; n < 4; ++n) acc[n] = splat4(b0[n]);
    #pragma unroll
    for (int pk = 0; pk < 2; ++pk){            // x chunks: operands already in regs
      #pragma unroll
      for (int n = 0; n < 4; ++n){
        short8 bfr = *(const short8*)(wlds + (n*NC0 + pk)*512 + lane*8);
        acc[n] = __builtin_amdgcn_mfma_f32_16x16x32_bf16(ahi[pk], bfr, acc[n], 0, 0, 0);
        acc[n] = __builtin_amdgcn_mfma_f32_16x16x32_bf16(alo[pk], bfr, acc[n], 0, 0, 0);
      }
    }
    vm_drain();                                // h0old/h1old now in regs
    #pragma unroll
    for (int pk = 2; pk < NC0; ++pk){
      #pragma unroll
      for (int n = 0; n < 4; ++n){
        short8 bfr = *(const short8*)(wlds + (n*NC0 + pk)*512 + lane*8);
        acc[n] = __builtin_amdgcn_mfma_f32_16x16x32_bf16(ahi[pk], bfr, acc[n], 0, 0, 0);
        acc[n] = __builtin_amdgcn_mfma_f32_16x16x32_bf16(alo[pk], bfr, acc[n], 0, 0, 0);
      }
    }
    { // pointwise + publish h0 slice (coherent stores)
      uint16_t* qh = h0hi[par]; uint16_t* ql = h0lo[par];
      #pragma unroll
      for (int r = 0; r < 4; ++r){
        float ig = sigm(acc[0][r]);
        float fg = sigm(acc[1][r]);
        float gg = tanhf_(acc[2][r]);
        float og = sigm(acc[3][r]);
        c0[r] = fg*c0[r] + ig*gg;
        float h = og*tanhf_(c0[r]);
        uint32_t hb = f2bf(h); float fh = bf2f(hb); uint32_t lb = f2bf(h - fh);
        size_t idx = (size_t)(drow + r)*256 + dcol;
        store_coh2(qh + idx, hb); store_coh2(ql + idx, lb);
      }
    }
    group_barrier(myc, 16*(2*t+1));

    // ================= layer 1 =================
    { // issue coherent loads of h0(t) into ahi/alo[0..7]
      const uint16_t* p0h = h0hi[par] + (size_t)arow*256 + ka;
      const uint16_t* p0l = h0lo[par] + (size_t)arow*256 + ka;
      #pragma unroll
      for (int kc = 0; kc < 8; ++kc){
        ahi[kc] = load_coh16(p0h + kc*32);
        alo[kc] = load_coh16(p0l + kc*32);
      }
    }
    #pragma unroll
    for (int n = 0; n < 4; ++n) acc[n] = splat4(b1[n]);
    #pragma unroll
    for (int pk = 8; pk < NC1; ++pk){          // h1old chunks: prefetched in bh/bl
      #pragma unroll
      for (int n = 0; n < 4; ++n){
        short8 bfr = *(const short8*)(wlds + L1_OFF + (n*NC1 + pk)*512 + lane*8);
        acc[n] = __builtin_amdgcn_mfma_f32_16x16x32_bf16(bh[pk-8], bfr, acc[n], 0, 0, 0);
        acc[n] = __builtin_amdgcn_mfma_f32_16x16x32_bf16(bl[pk-8], bfr, acc[n], 0, 0, 0);
      }
    }
    vm_drain();                                // h0new now in regs
    #pragma unroll
    for (int pk = 0; pk < 8; ++pk){
      #pragma unroll
      for (int n = 0; n < 4; ++n){
        short8 bfr = *(const short8*)(wlds + L1_OFF + (n*NC1 + pk)*512 + lane*8);
        acc[n] = __builtin_amdgcn_mfma_f32_16x16x32_bf16(ahi[pk], bfr, acc[n], 0, 0, 0);
        acc[n] = __builtin_amdgcn_mfma_f32_16x16x32_bf16(alo[pk], bfr, acc[n], 0, 0, 0);
      }
    }
    {
      uint16_t* qh = h1hi[par]; uint16_t* ql = h1lo[par];
      #pragma unroll
      for (int r = 0; r < 4; ++r){
        float ig = sigm(acc[0][r]);
        float fg = sigm(acc[1][r]);
        float gg = tanhf_(acc[2][r]);
        float og = sigm(acc[3][r]);
        c1[r] = fg*c1[r] + ig*gg;
        float h = og*tanhf_(c1[r]);
        uint32_t hb = f2bf(h); float fh = bf2f(hb); uint32_t lb = f2bf(h - fh);
        size_t idx = (size_t)(drow + r)*256 + dcol;
        store_coh2(qh + idx, hb); store_coh2(ql + idx, lb);
      }
    }
    group_barrier(myc, 16*(2*t+2));
  }

  // ---------------- FC epilogue: out[b] = h1_final(b,:) . fcw + fcb ----------------
  if (s == 0){
    const uint16_t* fh = h1hi[1];   // t=511 -> parity 1
    const uint16_t* fl = h1lo[1];
    const int rl = tid >> 2, seg = tid & 3;
    const int row = g*64 + rl;
    short8 vh[8], vl[8];
    #pragma unroll
    for (int c = 0; c < 8; ++c){
      vh[c] = load_coh16(fh + (size_t)row*256 + seg*64 + c*8);
      vl[c] = load_coh16(fl + (size_t)row*256 + seg*64 + c*8);
    }
    vm_drain();
    float sum = 0.f;
    #pragma unroll
    for (int c = 0; c < 8; ++c){
      #pragma unroll
      for (int j = 0; j < 8; ++j){
        int k = seg*64 + c*8 + j;
        sum += (bf2f((uint16_t)vh[c][j]) + bf2f((uint16_t)vl[c][j])) * fcw[k];
      }
    }
    sum += __shfl_down(sum, 1);
    sum += __shfl_down(sum, 2);
    if (seg == 0) out[row] = sum + fcb[0];
  }
}

// ---------------- host launch ----------------
extern "C" void kernel_launch(void* const* d_in, const int* in_sizes, int n_in,
                              void* d_out, int out_size, void* d_ws, size_t ws_size,
                              hipStream_t stream)
{
  (void)in_sizes; (void)n_in; (void)out_size; (void)ws_size;
  const float* x    = (const float*)d_in[0];
  const float* wih0 = (const float*)d_in[1];
  const float* whh0 = (const float*)d_in[2];
  const float* bih0 = (const float*)d_in[3];
  const float* bhh0 = (const float*)d_in[4];
  const float* wih1 = (const float*)d_in[5];
  const float* whh1 = (const float*)d_in[6];
  const float* bih1 = (const float*)d_in[7];
  const float* bhh1 = (const float*)d_in[8];
  const float* fcw  = (const float*)d_in[9];
  const float* fcb  = (const float*)d_in[10];

  char* ws = (char*)d_ws;
  const size_t SZ_WFRAG = (size_t)16*WSLICE_ELEMS*2;     // 1,703,936
  const size_t OFF_BIAS = SZ_WFRAG;
  const size_t OFF_CTR  = OFF_BIAS + (size_t)16*2*64*4;
  const size_t OFF_H    = (size_t)2*1024*1024;           // h buffers: 8 x 512KB

  uint16_t* wfrag = (uint16_t*)(ws);
  float*    biasg = (float*)(ws + OFF_BIAS);
  int*      ctr   = (int*)(ws + OFF_CTR);
  uint16_t* hbase = (uint16_t*)(ws + OFF_H);
  float*    out   = (float*)d_out;

  // zero barrier counters + h buffers; visibility to the coherent (sc1) data
  // path is guaranteed by end-of-dispatch L2 writeback of these prior ops.
  hipMemsetAsync(ws + OFF_CTR, 0, (OFF_H - OFF_CTR) + (size_t)8*HN*2, stream);

  hipLaunchKernelGGL(prep_weights, dim3(16*WSLICE_ELEMS/256), dim3(256), 0, stream,
                     wih0, whh0, wih1, whh1, wfrag);
  hipLaunchKernelGGL(prep_bias, dim3(8), dim3(256), 0, stream,
                     bih0, bhh0, bih1, bhh1, biasg);

  hipFuncSetAttribute((const void*)lstm_main,
                      hipFuncAttributeMaxDynamicSharedMemorySize, WSLICE_ELEMS*2);
  void* args[] = { (void*)&x, (void*)&wfrag, (void*)&biasg, (void*)&hbase,
                   (void*)&fcw, (void*)&fcb, (void*)&ctr, (void*)&out };
  hipLaunchCooperativeKernel((void*)lstm_main, dim3(256), dim3(256),
                             args, WSLICE_ELEMS*2, stream);
}

// Round 4
// 4642.271 us; speedup vs baseline: 5.2987x; 1.1610x over previous
//
#include <hip/hip_runtime.h>
#include <stdint.h>

// ---------------- geometry ----------------
// B=1024, T=512, I=64, H=256, gates 4H=1024 (i,f,g,o)
// 256 blocks = 16 slices (s) x 16 batch-groups (g); bid = s*16 + g
// block: 256 threads = 4 waves; wave w owns batch rows [g*64+w*16, +16)
// slice s owns h-columns [s*16, s*16+16) of BOTH layers
// Pipelined: super-step t computes L0(t) AND L1(t-1) -> ONE group barrier/step.
// h exchange: device-coherent (sc0 sc1) loads/stores, coherence point = L3.
// ALL in-loop vmem is inline asm; vmcnt ledger per iteration (t>0):
//   ops 1-16 : h0(t-1) loads      ops 17-32: h1(t-2) loads
//   ops 33-36: x(t+1) loads       ops 37-44: h0(t) stores
//   ops 45-52: h1(t-1) stores
//   VM_WAIT(20) -> ops<=16 retired (h0)      [36 issued]
//   VM_WAIT(12) -> ops<=32 retired (h1)      [44 issued]
//   VM_WAIT(8)  -> ops<=36 retired (x)       [44 issued; stores may linger]
//   VM_WAIT(0)  -> all stores acked, then group barrier
// NO runtime-indexed local arrays (scratch would pollute vmcnt counts).

#define T_STEPS 512
#define NC0 10
#define NC1 16
#define WSLICE_ELEMS (4*(NC0+NC1)*512)   // 53248 bf16 elems = 104KB
#define L1_OFF (4*NC0*512)               // 20480
#define HN (1024*256)                    // elems per h array

typedef __attribute__((ext_vector_type(8))) short short8;
typedef __attribute__((ext_vector_type(4))) float floatx4;

__device__ __forceinline__ uint32_t f2bf(float f){
  uint32_t u = __builtin_bit_cast(uint32_t, f);
  return (u + 0x7fffu + ((u >> 16) & 1u)) >> 16;   // RNE, finite data only
}
__device__ __forceinline__ float bf2f(uint32_t b){
  return __builtin_bit_cast(float, b << 16);
}
__device__ __forceinline__ float sigm(float x){
  return __builtin_amdgcn_rcpf(1.0f + __builtin_amdgcn_exp2f(-1.44269504f*x));
}
__device__ __forceinline__ float tanhf_(float x){
  return 1.0f - 2.0f*__builtin_amdgcn_rcpf(1.0f + __builtin_amdgcn_exp2f(2.88539008f*x));
}
__device__ __forceinline__ floatx4 splat4(float v){ return (floatx4){v,v,v,v}; }

__device__ __forceinline__ void cvt8(const floatx4& v0, const floatx4& v1, short8& hi, short8& lo){
  #pragma unroll
  for (int j = 0; j < 8; ++j){
    float f = (j < 4) ? v0[j] : v1[j-4];
    uint32_t hb = f2bf(f); float fh = bf2f(hb); uint32_t lb = f2bf(f - fh);
    hi[j] = (short)hb; lo[j] = (short)lb;
  }
}

// ---- coherent (sc0 sc1 -> L3 coherence point) and plain asm vmem ----
__device__ __forceinline__ short8 load_coh16(const uint16_t* p){
  short8 r;
  asm volatile("global_load_dwordx4 %0, %1, off sc0 sc1" : "=v"(r) : "v"(p));
  return r;
}
__device__ __forceinline__ floatx4 load_g16f(const float* p){
  floatx4 r;
  asm volatile("global_load_dwordx4 %0, %1, off" : "=v"(r) : "v"(p));
  return r;
}
__device__ __forceinline__ void store_coh2(uint16_t* p, uint32_t v){
  asm volatile("global_store_short %0, %1, off sc0 sc1" :: "v"(p), "v"(v) : "memory");
}
#define VM_WAIT(N) do{ asm volatile("s_waitcnt vmcnt(" #N ")" ::: "memory"); \
                       __builtin_amdgcn_sched_barrier(0); }while(0)

// ---------------- prep: gather weights into per-slice B-fragment images ----------------
extern "C" __global__ void prep_weights(const float* __restrict__ wih0, const float* __restrict__ whh0,
                                        const float* __restrict__ wih1, const float* __restrict__ whh1,
                                        uint16_t* __restrict__ wfrag)
{
  int idx = blockIdx.x*256 + threadIdx.x;     // exactly 16*WSLICE_ELEMS threads
  int s  = idx / WSLICE_ELEMS;
  int r  = idx - s*WSLICE_ELEMS;
  int layer = (r >= L1_OFF) ? 1 : 0;
  int rr = layer ? (r - L1_OFF) : r;
  int nc = layer ? NC1 : NC0;
  int n  = rr / (nc*512);
  int c  = (rr / 512) % nc;
  int l  = (rr >> 3) & 63;
  int j  = rr & 7;
  int k  = c*32 + ((l >> 4) << 3) + j;        // B frag: lane l holds col=l&15, k=8*(l>>4)+j
  int grow = n*256 + s*16 + (l & 15);
  float v;
  if (!layer) v = (k < 64)  ? wih0[grow*64  + k] : whh0[grow*256 + (k - 64)];
  else        v = (k < 256) ? wih1[grow*256 + k] : whh1[grow*256 + (k - 256)];
  wfrag[idx] = (uint16_t)f2bf(v);
}

extern "C" __global__ void prep_bias(const float* __restrict__ bih0, const float* __restrict__ bhh0,
                                     const float* __restrict__ bih1, const float* __restrict__ bhh1,
                                     float* __restrict__ biasg)
{
  int idx = blockIdx.x*256 + threadIdx.x;     // 16 slices * 2 layers * 64
  if (idx >= 16*2*64) return;
  int s = idx >> 7;
  int layer = (idx >> 6) & 1;
  int q = idx & 63;
  int grow = (q >> 4)*256 + s*16 + (q & 15);
  biasg[idx] = layer ? (bih1[grow] + bhh1[grow]) : (bih0[grow] + bhh0[grow]);
}

// ---------------- main persistent kernel ----------------
extern "C" __global__ void __launch_bounds__(256, 1)
lstm_main(const float* __restrict__ x,
          const uint16_t* __restrict__ wfrag,
          const float* __restrict__ biasg,
          uint16_t* __restrict__ hbase,
          const float* __restrict__ fcw,
          const float* __restrict__ fcb,
          int* __restrict__ ctr,
          float* __restrict__ out)
{
  extern __shared__ uint16_t wlds[];
  const int tid  = threadIdx.x;
  const int bid  = blockIdx.x;
  const int s    = bid >> 4;
  const int g    = bid & 15;
  const int wv   = tid >> 6;
  const int lane = tid & 63;

  // A-frag addressing: lane holds row = lane&15 (+wave base), k = 8*(lane>>4)+j
  const int arow = g*64 + wv*16 + (lane & 15);
  const int ka   = (lane >> 4) * 8;
  // D-frag addressing: col = lane&15, row = 4*(lane>>4)+reg
  const int drow = g*64 + wv*16 + ((lane >> 4) << 2);
  const int dcol = s*16 + (lane & 15);

  { // stage weight slice (104KB) into LDS
    const uint16_t* wsrc = wfrag + (size_t)s*WSLICE_ELEMS;
    for (int i = tid*8; i < WSLICE_ELEMS; i += 256*8)
      *(short8*)(wlds + i) = *(const short8*)(wsrc + i);
  }
  // preload biases, fc weight element, x(0): plain pre-loop loads (compiler-
  // waited); no in-loop scratch -> counted vmcnts stay exact
  float b0[4], b1[4];
  {
    const int col = lane & 15;
    #pragma unroll
    for (int n = 0; n < 4; ++n){
      b0[n] = biasg[(s*2+0)*64 + n*16 + col];
      b1[n] = biasg[(s*2+1)*64 + n*16 + col];
    }
  }
  const float fcwv = fcw[dcol];
  const float fcb0 = fcb[0];

  short8 xh[2], xl[2];
  {
    const float* xp = x + (size_t)arow*T_STEPS*64 + ka;
    floatx4 v0 = *(const floatx4*)(xp);
    floatx4 v1 = *(const floatx4*)(xp + 4);
    floatx4 v2 = *(const floatx4*)(xp + 32);
    floatx4 v3 = *(const floatx4*)(xp + 36);
    cvt8(v0, v1, xh[0], xl[0]);
    cvt8(v2, v3, xh[1], xl[1]);
  }
  __syncthreads();

  // h buffer layout: h0hi[p]=hbase+p*HN, h0lo[p]=+2HN, h1hi[p]=+4HN, h1lo[p]=+6HN
  const size_t abase = (size_t)arow*256 + ka;   // A-frag element offset
  float c0[4] = {0,0,0,0}, c1[4] = {0,0,0,0};
  int* myc = ctr + g*32;               // 128B apart: no line sharing between groups

  for (int t = 0; t < T_STEPS; ++t){
    const size_t par0  = (size_t)(t & 1);   // h0(t) write / h1(t-2) read parity
    const size_t rpar0 = par0 ^ 1;          // h0(t-1) read / h1(t-1) write parity

    short8 a0h[8], a0l[8], a1h[8], a1l[8];
    { // ops 1-16: h0(t-1)
      const uint16_t* ph = hbase + rpar0*HN              + abase;
      const uint16_t* pl = hbase + 2*(size_t)HN + rpar0*HN + abase;
      #pragma unroll
      for (int kc = 0; kc < 8; ++kc) a0h[kc] = load_coh16(ph + kc*32);
      #pragma unroll
      for (int kc = 0; kc < 8; ++kc) a0l[kc] = load_coh16(pl + kc*32);
    }
    { // ops 17-32: h1(t-2)
      const uint16_t* ph = hbase + 4*(size_t)HN + par0*HN + abase;
      const uint16_t* pl = hbase + 6*(size_t)HN + par0*HN + abase;
      #pragma unroll
      for (int kc = 0; kc < 8; ++kc) a1h[kc] = load_coh16(ph + kc*32);
      #pragma unroll
      for (int kc = 0; kc < 8; ++kc) a1l[kc] = load_coh16(pl + kc*32);
    }
    // ops 33-36: x(t+1) prefetch (plain loads)
    floatx4 xr0, xr1, xr2, xr3;
    {
      const int tn = (t < T_STEPS-1) ? (t+1) : t;
      const float* xp = x + ((size_t)arow*T_STEPS + tn)*64 + ka;
      xr0 = load_g16f(xp);      xr1 = load_g16f(xp + 4);
      xr2 = load_g16f(xp + 32); xr3 = load_g16f(xp + 36);
    }

    // ---- x-chunk MFMAs while loads fly (x frags prepared last iteration) ----
    floatx4 acc0[4], acc1[4];
    #pragma unroll
    for (int n = 0; n < 4; ++n) acc0[n] = splat4(b0[n]);
    #pragma unroll
    for (int pk = 0; pk < 2; ++pk){
      #pragma unroll
      for (int n = 0; n < 4; ++n){
        short8 w = *(const short8*)(wlds + (n*NC0 + pk)*512 + lane*8);
        acc0[n] = __builtin_amdgcn_mfma_f32_16x16x32_bf16(xh[pk], w, acc0[n], 0, 0, 0);
        acc0[n] = __builtin_amdgcn_mfma_f32_16x16x32_bf16(xl[pk], w, acc0[n], 0, 0, 0);
      }
    }
    #pragma unroll
    for (int n = 0; n < 4; ++n) acc1[n] = splat4(b1[n]);

    VM_WAIT(20);                        // 36 issued - 20 = 16: h0(t-1) in regs

    // ---- shared-A block: L0 W_hh0 + L1 W_ih1, both consume h0(t-1) ----
    #pragma unroll
    for (int kc = 0; kc < 8; ++kc){
      #pragma unroll
      for (int n = 0; n < 4; ++n){
        short8 w0 = *(const short8*)(wlds + (n*NC0 + 2 + kc)*512 + lane*8);
        acc0[n] = __builtin_amdgcn_mfma_f32_16x16x32_bf16(a0h[kc], w0, acc0[n], 0, 0, 0);
        acc0[n] = __builtin_amdgcn_mfma_f32_16x16x32_bf16(a0l[kc], w0, acc0[n], 0, 0, 0);
        short8 w1 = *(const short8*)(wlds + L1_OFF + (n*NC1 + kc)*512 + lane*8);
        acc1[n] = __builtin_amdgcn_mfma_f32_16x16x32_bf16(a0h[kc], w1, acc1[n], 0, 0, 0);
        acc1[n] = __builtin_amdgcn_mfma_f32_16x16x32_bf16(a0l[kc], w1, acc1[n], 0, 0, 0);
      }
    }

    // ---- L0 pointwise + publish h0(t): store ops 37-44 ----
    {
      uint16_t* qh = hbase + par0*HN;
      uint16_t* ql = hbase + 2*(size_t)HN + par0*HN;
      #pragma unroll
      for (int r = 0; r < 4; ++r){
        float ig = sigm(acc0[0][r]);
        float fg = sigm(acc0[1][r]);
        float gg = tanhf_(acc0[2][r]);
        float og = sigm(acc0[3][r]);
        c0[r] = fg*c0[r] + ig*gg;
        float h = og*tanhf_(c0[r]);
        uint32_t hb = f2bf(h); float fh = bf2f(hb); uint32_t lb = f2bf(h - fh);
        size_t idx = (size_t)(drow + r)*256 + dcol;
        store_coh2(qh + idx, hb); store_coh2(ql + idx, lb);
      }
    }

    VM_WAIT(12);                        // 44 - 12 = 32: h1(t-2) in regs

    // ---- L1 W_hh1 MFMAs (x loads + store acks overlap underneath) ----
    #pragma unroll
    for (int kc = 0; kc < 8; ++kc){
      #pragma unroll
      for (int n = 0; n < 4; ++n){
        short8 w1 = *(const short8*)(wlds + L1_OFF + (n*NC1 + 8 + kc)*512 + lane*8);
        acc1[n] = __builtin_amdgcn_mfma_f32_16x16x32_bf16(a1h[kc], w1, acc1[n], 0, 0, 0);
        acc1[n] = __builtin_amdgcn_mfma_f32_16x16x32_bf16(a1l[kc], w1, acc1[n], 0, 0, 0);
      }
    }

    VM_WAIT(8);                         // 44 - 8 = 36: x(t+1) in regs (stores may linger)
    cvt8(xr0, xr1, xh[0], xl[0]);
    cvt8(xr2, xr3, xh[1], xl[1]);

    // ---- L1 pointwise + publish h1(t-1): store ops 45-52 [skipped at t=0] ----
    if (t > 0){
      uint16_t* qh = hbase + 4*(size_t)HN + rpar0*HN;
      uint16_t* ql = hbase + 6*(size_t)HN + rpar0*HN;
      #pragma unroll
      for (int r = 0; r < 4; ++r){
        float ig = sigm(acc1[0][r]);
        float fg = sigm(acc1[1][r]);
        float gg = tanhf_(acc1[2][r]);
        float og = sigm(acc1[3][r]);
        c1[r] = fg*c1[r] + ig*gg;
        float h = og*tanhf_(c1[r]);
        uint32_t hb = f2bf(h); float fh = bf2f(hb); uint32_t lb = f2bf(h - fh);
        size_t idx = (size_t)(drow + r)*256 + dcol;
        store_coh2(qh + idx, hb); store_coh2(ql + idx, lb);
      }
    }

    VM_WAIT(0);                         // all coherent stores globally visible

    // ---- single group barrier per super-step ----
    __syncthreads();
    if (tid == 0){
      __hip_atomic_fetch_add(myc, 1, __ATOMIC_RELAXED, __HIP_MEMORY_SCOPE_AGENT);
      const int target = 16*(t+1);
      int spins = 0;
      while (__hip_atomic_load(myc, __ATOMIC_RELAXED, __HIP_MEMORY_SCOPE_AGENT) < target){
        if (++spins > (1<<20)) break;   // bounded: fail loud, never hang
        __builtin_amdgcn_s_sleep(1);
      }
    }
    __syncthreads();
  }

  // ---------------- epilogue: compute L1(511) locally, fused FC via atomicAdd ----------------
  {
    const uint16_t* p0h = hbase + 1*(size_t)HN + abase;   // h0(511) hi, parity 1
    const uint16_t* p0l = hbase + 3*(size_t)HN + abase;   // h0(511) lo
    const uint16_t* p1h = hbase + 4*(size_t)HN + abase;   // h1(510) hi, parity 0
    const uint16_t* p1l = hbase + 6*(size_t)HN + abase;   // h1(510) lo
    short8 a0h[8], a0l[8], a1h[8], a1l[8];
    #pragma unroll
    for (int kc = 0; kc < 8; ++kc){
      a0h[kc] = load_coh16(p0h + kc*32);
      a0l[kc] = load_coh16(p0l + kc*32);
      a1h[kc] = load_coh16(p1h + kc*32);
      a1l[kc] = load_coh16(p1l + kc*32);
    }
    VM_WAIT(0);
    floatx4 acc[4];
    #pragma unroll
    for (int n = 0; n < 4; ++n) acc[n] = splat4(b1[n]);
    #pragma unroll
    for (int kc = 0; kc < 8; ++kc){
      #pragma unroll
      for (int n = 0; n < 4; ++n){
        short8 w1 = *(const short8*)(wlds + L1_OFF + (n*NC1 + kc)*512 + lane*8);
        acc[n] = __builtin_amdgcn_mfma_f32_16x16x32_bf16(a0h[kc], w1, acc[n], 0, 0, 0);
        acc[n] = __builtin_amdgcn_mfma_f32_16x16x32_bf16(a0l[kc], w1, acc[n], 0, 0, 0);
        short8 w2 = *(const short8*)(wlds + L1_OFF + (n*NC1 + 8 + kc)*512 + lane*8);
        acc[n] = __builtin_amdgcn_mfma_f32_16x16x32_bf16(a1h[kc], w2, acc[n], 0, 0, 0);
        acc[n] = __builtin_amdgcn_mfma_f32_16x16x32_bf16(a1l[kc], w2, acc[n], 0, 0, 0);
      }
    }
    #pragma unroll
    for (int r = 0; r < 4; ++r){
      float ig = sigm(acc[0][r]);
      float fg = sigm(acc[1][r]);
      float gg = tanhf_(acc[2][r]);
      float og = sigm(acc[3][r]);
      float cc = fg*c1[r] + ig*gg;
      float h  = og*tanhf_(cc);
      float v  = h * fcwv;
      v += __shfl_xor(v, 1);
      v += __shfl_xor(v, 2);
      v += __shfl_xor(v, 4);
      v += __shfl_xor(v, 8);
      if ((lane & 15) == 0){
        float res = v + ((s == 0) ? fcb0 : 0.0f);
        atomicAdd(out + drow + r, res);
      }
    }
  }
}

// ---------------- host launch ----------------
extern "C" void kernel_launch(void* const* d_in, const int* in_sizes, int n_in,
                              void* d_out, int out_size, void* d_ws, size_t ws_size,
                              hipStream_t stream)
{
  (void)in_sizes; (void)n_in; (void)out_size; (void)ws_size;
  const float* x    = (const float*)d_in[0];
  const float* wih0 = (const float*)d_in[1];
  const float* whh0 = (const float*)d_in[2];
  const float* bih0 = (const float*)d_in[3];
  const float* bhh0 = (const float*)d_in[4];
  const float* wih1 = (const float*)d_in[5];
  const float* whh1 = (const float*)d_in[6];
  const float* bih1 = (const float*)d_in[7];
  const float* bhh1 = (const float*)d_in[8];
  const float* fcw  = (const float*)d_in[9];
  const float* fcb  = (const float*)d_in[10];

  char* ws = (char*)d_ws;
  const size_t SZ_WFRAG = (size_t)16*WSLICE_ELEMS*2;     // 1,703,936
  const size_t OFF_BIAS = SZ_WFRAG;
  const size_t OFF_CTR  = OFF_BIAS + (size_t)16*2*64*4;
  const size_t OFF_H    = (size_t)2*1024*1024;           // h buffers: 8 x 512KB

  uint16_t* wfrag = (uint16_t*)(ws);
  float*    biasg = (float*)(ws + OFF_BIAS);
  int*      ctr   = (int*)(ws + OFF_CTR);
  uint16_t* hbase = (uint16_t*)(ws + OFF_H);
  float*    out   = (float*)d_out;

  // zero out (atomicAdd accumulator), barrier counters, h double-buffers
  hipMemsetAsync(d_out, 0, (size_t)1024*sizeof(float), stream);
  hipMemsetAsync(ws + OFF_CTR, 0, (OFF_H - OFF_CTR) + (size_t)8*HN*2, stream);

  hipLaunchKernelGGL(prep_weights, dim3(16*WSLICE_ELEMS/256), dim3(256), 0, stream,
                     wih0, whh0, wih1, whh1, wfrag);
  hipLaunchKernelGGL(prep_bias, dim3(8), dim3(256), 0, stream,
                     bih0, bhh0, bih1, bhh1, biasg);

  hipFuncSetAttribute((const void*)lstm_main,
                      hipFuncAttributeMaxDynamicSharedMemorySize, WSLICE_ELEMS*2);
  void* args[] = { (void*)&x, (void*)&wfrag, (void*)&biasg, (void*)&hbase,
                   (void*)&fcw, (void*)&fcb, (void*)&ctr, (void*)&out };
  hipError_t ce = hipLaunchCooperativeKernel((void*)lstm_main, dim3(256), dim3(256),
                                             args, WSLICE_ELEMS*2, stream);
  if (ce != hipSuccess){
    // fallback: plain launch. 104KB dynamic LDS forces 1 block/CU; grid=256 on a
    // 256-CU chip -> all blocks resident, spin barrier remains safe.
    hipLaunchKernelGGL(lstm_main, dim3(256), dim3(256), WSLICE_ELEMS*2, stream,
                       x, wfrag, biasg, hbase, fcw, fcb, ctr, out);
  }
}